// Round 1
// baseline (266.315 us; speedup 1.0000x reference)
//
#include <hip/hip_runtime.h>
#include <hip/hip_fp16.h>

// Problem constants (H=W=2048, C=3, KSIZE=2, SIGMA=2, ITERATIONS=2)
#define Hh 2048
#define Ww 2048
#define HW (2048 * 2048)
constexpr int REG = 2045;              // Hv = Wv = H - 2*KSIZE + 1
constexpr int RBASE = 2 * 2045 * 2045; // per-iteration order stride = 8364050
constexpr int SWAP_D2 = 589824;        // 768^2
constexpr int CLEAN_D2 = 586756;       // 766^2

// Gaussian kernel sigma=2, truncate=4 -> radius 8, normalized (precomputed)
__device__ __constant__ float GK[17] = {
    6.691628e-05f, 4.363490e-04f, 2.215963e-03f, 8.764304e-03f,
    2.699596e-02f, 6.475994e-02f, 1.209875e-01f, 1.760358e-01f,
    1.9947466e-01f, 1.760358e-01f, 1.209875e-01f, 6.475994e-02f,
    2.699596e-02f, 8.764304e-03f, 2.215963e-03f, 4.363490e-04f,
    6.691628e-05f};

// Pass 1: scatter-max of (order+1) into win[]. Orders are globally unique so a
// single atomicMax resolves the reference's 4-list scatter-max exactly.
// For the self-write (tgt = lin), iteration 1's order always beats iteration
// 0's, so one atomic suffices for it -> 3 atomics per swap pixel.
__global__ void scatter_win(const int* __restrict__ off, int* __restrict__ win) {
  int x = blockIdx.x * 256 + threadIdx.x;
  int y = blockIdx.y;
  if (x >= REG) return;
  int Hc = y + 2, Wc = x + 2;
  int dx = 1024 - Wc, dy = 1024 - Hc;
  if (dx * dx + dy * dy < SWAP_D2) return;  // swap_mask false -> no writes matter
  int lin = Hc * Ww + Wc;
  int local2 = 2 * (y * REG + x);
  // write1 (tgt = lin, order = i*RBASE + local2); i=1 dominates:
  atomicMax(&win[lin], RBASE + local2 + 1);
#pragma unroll
  for (int i = 0; i < 2; ++i) {
    const int2 o = *(const int2*)&off[(((i * REG + y) * REG) + x) * 2];
    int lin2 = (Hc + o.x) * Ww + (Wc + o.y);
    // write2 (tgt = lin_, order = i*RBASE + local2 + 1); store order+1:
    atomicMax(&win[lin2], i * RBASE + local2 + 2);
  }
}

// Pass 2: decode winning order -> src pixel, gather, write fp16 planar planes.
__global__ void resolve_swap(const float* __restrict__ img,
                             const int* __restrict__ off,
                             const int* __restrict__ win,
                             __half* __restrict__ A) {
  int p = blockIdx.x * 256 + threadIdx.x;
  int w = win[p];
  int src = p;
  if (w > 0) {
    int order = w - 1;
    int i = order >= RBASE ? 1 : 0;
    int rem = order - i * RBASE;
    int which = rem & 1;     // 0: tgt=lin, src=lin_ ; 1: tgt=lin_, src=lin
    int local = rem >> 1;
    int yy = local / REG;
    int xx = local - yy * REG;
    int Hc = yy + 2, Wc = xx + 2;
    const int2 o = *(const int2*)&off[(((i * REG + yy) * REG) + xx) * 2];
    src = which ? (Hc * Ww + Wc) : ((Hc + o.x) * Ww + (Wc + o.y));
  }
  float r = img[src * 3 + 0];
  float g = img[src * 3 + 1];
  float b = img[src * 3 + 2];
  A[p] = __float2half(r);
  A[HW + p] = __float2half(g);
  A[2 * HW + p] = __float2half(b);
}

// Pass 3: vertical 17-tap blur, register-tiled: 16 rows x 2 cols per thread.
constexpr int YPT = 16;
__global__ void vblur(const __half* __restrict__ A, __half* __restrict__ B) {
  int x0 = (blockIdx.x * 256 + threadIdx.x) * 2;
  int y0 = blockIdx.y * YPT;
  const __half* Ap = A + (size_t)blockIdx.z * HW;
  __half* Bp = B + (size_t)blockIdx.z * HW;
  float2 acc[YPT];
#pragma unroll
  for (int k = 0; k < YPT; ++k) acc[k] = make_float2(0.f, 0.f);
#pragma unroll
  for (int j = 0; j < YPT + 16; ++j) {
    int ys = y0 - 8 + j;
    ys = ys < 0 ? 0 : (ys > Hh - 1 ? Hh - 1 : ys);  // mode='nearest'
    __half2 h = *(const __half2*)&Ap[ys * Ww + x0];
    float2 v = __half22float2(h);
#pragma unroll
    for (int k = 0; k < YPT; ++k) {
      int t = j - k;
      if (t >= 0 && t <= 16) {
        acc[k].x += GK[t] * v.x;
        acc[k].y += GK[t] * v.y;
      }
    }
  }
#pragma unroll
  for (int k = 0; k < YPT; ++k) {
    *(__half2*)&Bp[(y0 + k) * Ww + x0] = __float22half2_rn(acc[k]);
  }
}

// Pass 4: horizontal 17-tap blur via LDS row tile + clip + compose with clean
// circle (original pixels where d2 < 766^2 inside the valid region).
__global__ void hblur_compose(const __half* __restrict__ B,
                              const float* __restrict__ img,
                              float* __restrict__ out) {
  __shared__ float tile[256 + 16];
  int tid = threadIdx.x;
  int xs = blockIdx.x * 256;
  int y = blockIdx.y;
  int x = xs + tid;
  float br[3];
  for (int c = 0; c < 3; ++c) {
    const __half* Bp = B + (size_t)c * HW + (size_t)y * Ww;
    __syncthreads();
    int xg = xs - 8 + tid;
    xg = xg < 0 ? 0 : (xg > Ww - 1 ? Ww - 1 : xg);
    tile[tid] = __half2float(Bp[xg]);
    if (tid < 16) {
      int xg2 = xs - 8 + 256 + tid;
      xg2 = xg2 > Ww - 1 ? Ww - 1 : xg2;
      tile[256 + tid] = __half2float(Bp[xg2]);
    }
    __syncthreads();
    float s = 0.f;
#pragma unroll
    for (int j = 0; j < 17; ++j) s += GK[j] * tile[tid + j];
    br[c] = s;
  }
  int dx = 1024 - x, dy = 1024 - y;
  int d2 = dx * dx + dy * dy;
  bool clean = (x >= 2 && x <= 2046 && y >= 2 && y <= 2046 && d2 < CLEAN_D2);
  int p3 = (y * Ww + x) * 3;
  if (clean) {
    out[p3 + 0] = img[p3 + 0];
    out[p3 + 1] = img[p3 + 1];
    out[p3 + 2] = img[p3 + 2];
  } else {
#pragma unroll
    for (int c = 0; c < 3; ++c) {
      float v = br[c];
      v = v < 0.f ? 0.f : (v > 255.f ? 255.f : v);  // == clip(v/255,0,1)*255
      out[p3 + c] = v;
    }
  }
}

extern "C" void kernel_launch(void* const* d_in, const int* in_sizes, int n_in,
                              void* d_out, int out_size, void* d_ws,
                              size_t ws_size, hipStream_t stream) {
  const float* img = (const float*)d_in[0];
  const int* off = (const int*)d_in[1];
  float* out = (float*)d_out;

  // Workspace layout: win (int32, 16 MB) | A (fp16 x 3 planes, 24 MB) |
  //                   B (fp16 x 3 planes, 24 MB)  -> 64 MB total
  int* win = (int*)d_ws;
  __half* A = (__half*)((char*)d_ws + (size_t)HW * 4);
  __half* Bp = A + (size_t)3 * HW;

  hipMemsetAsync(win, 0, (size_t)HW * 4, stream);
  scatter_win<<<dim3(8, REG), 256, 0, stream>>>(off, win);
  resolve_swap<<<HW / 256, 256, 0, stream>>>(img, off, win, A);
  vblur<<<dim3(4, Hh / YPT, 3), 256, 0, stream>>>(A, Bp);
  hblur_compose<<<dim3(Ww / 256, Hh), 256, 0, stream>>>(Bp, img, out);
}

// Round 2
// 187.512 us; speedup vs baseline: 1.4203x; 1.4203x over previous
//
#include <hip/hip_runtime.h>
#include <hip/hip_fp16.h>

// Problem constants (H=W=2048, C=3, KSIZE=2, SIGMA=2, ITERATIONS=2)
#define Hh 2048
#define Ww 2048
#define HW (2048 * 2048)
constexpr int REG = 2045;              // Hv = Wv = H - 2*KSIZE + 1
constexpr int RBASE = 2 * 2045 * 2045; // per-iteration order stride (also i-plane
                                       // stride of `off` in elements = REG*REG*2)
constexpr int SWAP_D2 = 589824;        // 768^2
constexpr int CLEAN_D2 = 586756;       // 766^2

// Gaussian kernel sigma=2, truncate=4 -> radius 8, normalized (precomputed)
__device__ __constant__ float GK[17] = {
    6.691628e-05f, 4.363490e-04f, 2.215963e-03f, 8.764304e-03f,
    2.699596e-02f, 6.475994e-02f, 1.209875e-01f, 1.760358e-01f,
    1.9947466e-01f, 1.760358e-01f, 1.209875e-01f, 6.475994e-02f,
    2.699596e-02f, 8.764304e-03f, 2.215963e-03f, 4.363490e-04f,
    6.691628e-05f};

// ---------------------------------------------------------------------------
// Pass 1 (fused): gather-formulated glass swap + fp16 planar repack.
// A writer q only writes targets q+d, d in [-2,1]^2, so target p has 16
// candidate writers q in [p-1,p+2]^2 per iteration (+ the self-write, where
// i=1 always beats i=0). Orders are affine in q, so each candidate's order is
// a constant offset from a per-pixel base. Region mask is folded into the LDS
// stage as a sentinel. No atomics, no win[] array, no memset.
// ---------------------------------------------------------------------------
constexpr int TX = 32, TY = 8;       // pixels per block (256 threads, 1 px/thread)
constexpr int HX = TX + 3, HY = TY + 3;  // q-halo: [x0-1, x0+TX+1]

__global__ __launch_bounds__(256) void swap_gather(
    const float* __restrict__ img, const int* __restrict__ off,
    __half* __restrict__ A) {
  int x0 = blockIdx.x * TX, y0 = blockIdx.y * TY;
  int tx = threadIdx.x & 31, ty = threadIdx.x >> 5;
  int px = x0 + tx, py = y0 + ty;
  int plin = py * Ww + px;
  int src = plin;

  // Block-uniform fast path: if the entire q-halo is inside the clean circle,
  // no writer can exist -> src = p for the whole tile.
  int mxx = max(abs(1024 - (x0 - 1)), abs(1024 - (x0 + TX + 1)));
  int mxy = max(abs(1024 - (y0 - 1)), abs(1024 - (y0 + TY + 1)));
  if (mxx * mxx + mxy * mxy >= SWAP_D2) {
    __shared__ int4 sh[HY * HX];  // {dh0, dw0, dh1, dw1} per q
    for (int e = threadIdx.x; e < HY * HX; e += 256) {
      int ly = e / HX, lx = e - ly * HX;
      int qy = y0 - 1 + ly, qx = x0 - 1 + lx;
      int4 v = make_int4(100, 100, 100, 100);  // sentinel: never matches d
      int dcx = 1024 - qx, dcy = 1024 - qy;
      if (qy >= 2 && qy <= 2046 && qx >= 2 && qx <= 2046 &&
          dcx * dcx + dcy * dcy >= SWAP_D2) {
        int base = ((qy - 2) * REG + (qx - 2)) * 2;
        const int2 a0 = *(const int2*)&off[base];
        const int2 a1 = *(const int2*)&off[RBASE + base];
        v = make_int4(a0.x, a0.y, a1.x, a1.y);
      }
      sh[e] = v;
    }
    __syncthreads();

    int best = -1;
    int base0 = 2 * ((py - 2) * REG + (px - 2)) + 1;  // write2 order at q==p
    // self-write (write1, i=1): order = RBASE + 2*locp, src = p + off[1,p]
    {
      int dcx = 1024 - px, dcy = 1024 - py;
      if (px >= 2 && px <= 2046 && py >= 2 && py <= 2046 &&
          dcx * dcx + dcy * dcy >= SWAP_D2) {
        best = RBASE + base0 - 1;
        int4 v = sh[(ty + 1) * HX + (tx + 1)];
        src = plin + v.z * Ww + v.w;
      }
    }
#pragma unroll
    for (int dyi = 0; dyi < 4; ++dyi) {
      int ddy = 1 - dyi;  // qy = py - ddy
#pragma unroll
      for (int dxi = 0; dxi < 4; ++dxi) {
        int ddx = 1 - dxi;  // qx = px - ddx
        int4 v = sh[(ty + dyi) * HX + (tx + dxi)];
        int ordc = base0 - 2 * (ddy * REG + ddx);  // i=0 write2 order
        int qlin = plin - ddy * Ww - ddx;
        bool h0 = (v.x == ddy) & (v.y == ddx);
        bool h1 = (v.z == ddy) & (v.w == ddx);
        if (h0 & (ordc > best)) { best = ordc; src = qlin; }
        int ord1 = ordc + RBASE;
        if (h1 & (ord1 > best)) { best = ord1; src = qlin; }
      }
    }
  }

  float r = img[src * 3 + 0];
  float g = img[src * 3 + 1];
  float b = img[src * 3 + 2];
  A[plin] = __float2half(r);
  A[HW + plin] = __float2half(g);
  A[2 * HW + plin] = __float2half(b);
}

// ---------------------------------------------------------------------------
// Pass 2: vertical 17-tap blur, register-tiled: 16 rows x 2 cols per thread.
// ---------------------------------------------------------------------------
constexpr int YPT = 16;
__global__ void vblur(const __half* __restrict__ A, __half* __restrict__ B) {
  int x0 = (blockIdx.x * 256 + threadIdx.x) * 2;
  int y0 = blockIdx.y * YPT;
  const __half* Ap = A + (size_t)blockIdx.z * HW;
  __half* Bp = B + (size_t)blockIdx.z * HW;
  float2 acc[YPT];
#pragma unroll
  for (int k = 0; k < YPT; ++k) acc[k] = make_float2(0.f, 0.f);
#pragma unroll
  for (int j = 0; j < YPT + 16; ++j) {
    int ys = y0 - 8 + j;
    ys = ys < 0 ? 0 : (ys > Hh - 1 ? Hh - 1 : ys);  // mode='nearest'
    __half2 h = *(const __half2*)&Ap[ys * Ww + x0];
    float2 v = __half22float2(h);
#pragma unroll
    for (int k = 0; k < YPT; ++k) {
      int t = j - k;
      if (t >= 0 && t <= 16) {
        acc[k].x += GK[t] * v.x;
        acc[k].y += GK[t] * v.y;
      }
    }
  }
#pragma unroll
  for (int k = 0; k < YPT; ++k) {
    *(__half2*)&Bp[(y0 + k) * Ww + x0] = __float22half2_rn(acc[k]);
  }
}

// ---------------------------------------------------------------------------
// Pass 3: horizontal 17-tap blur via LDS row tile + clip + compose with clean
// circle (original pixels where d2 < 766^2 inside the valid region).
// ---------------------------------------------------------------------------
__global__ void hblur_compose(const __half* __restrict__ B,
                              const float* __restrict__ img,
                              float* __restrict__ out) {
  __shared__ float tile[256 + 16];
  int tid = threadIdx.x;
  int xs = blockIdx.x * 256;
  int y = blockIdx.y;
  int x = xs + tid;
  float br[3];
  for (int c = 0; c < 3; ++c) {
    const __half* Bp = B + (size_t)c * HW + (size_t)y * Ww;
    __syncthreads();
    int xg = xs - 8 + tid;
    xg = xg < 0 ? 0 : (xg > Ww - 1 ? Ww - 1 : xg);
    tile[tid] = __half2float(Bp[xg]);
    if (tid < 16) {
      int xg2 = xs - 8 + 256 + tid;
      xg2 = xg2 > Ww - 1 ? Ww - 1 : xg2;
      tile[256 + tid] = __half2float(Bp[xg2]);
    }
    __syncthreads();
    float s = 0.f;
#pragma unroll
    for (int j = 0; j < 17; ++j) s += GK[j] * tile[tid + j];
    br[c] = s;
  }
  int dx = 1024 - x, dy = 1024 - y;
  int d2 = dx * dx + dy * dy;
  bool clean = (x >= 2 && x <= 2046 && y >= 2 && y <= 2046 && d2 < CLEAN_D2);
  int p3 = (y * Ww + x) * 3;
  if (clean) {
    out[p3 + 0] = img[p3 + 0];
    out[p3 + 1] = img[p3 + 1];
    out[p3 + 2] = img[p3 + 2];
  } else {
#pragma unroll
    for (int c = 0; c < 3; ++c) {
      float v = br[c];
      v = v < 0.f ? 0.f : (v > 255.f ? 255.f : v);  // == clip(v/255,0,1)*255
      out[p3 + c] = v;
    }
  }
}

extern "C" void kernel_launch(void* const* d_in, const int* in_sizes, int n_in,
                              void* d_out, int out_size, void* d_ws,
                              size_t ws_size, hipStream_t stream) {
  const float* img = (const float*)d_in[0];
  const int* off = (const int*)d_in[1];
  float* out = (float*)d_out;

  // Workspace layout: A (fp16 x 3 planes, 24 MB) | B (fp16 x 3 planes, 24 MB)
  __half* A = (__half*)d_ws;
  __half* Bp = A + (size_t)3 * HW;

  swap_gather<<<dim3(Ww / TX, Hh / TY), 256, 0, stream>>>(img, off, A);
  vblur<<<dim3(4, Hh / YPT, 3), 256, 0, stream>>>(A, Bp);
  hblur_compose<<<dim3(Ww / 256, Hh), 256, 0, stream>>>(Bp, img, out);
}

// Round 3
// 179.467 us; speedup vs baseline: 1.4839x; 1.0448x over previous
//
#include <hip/hip_runtime.h>
#include <hip/hip_fp16.h>

// Problem constants (H=W=2048, C=3, KSIZE=2, SIGMA=2, ITERATIONS=2)
#define Hh 2048
#define Ww 2048
#define HW (2048 * 2048)
constexpr int REG = 2045;              // Hv = Wv = H - 2*KSIZE + 1
constexpr int RBASE = 2 * 2045 * 2045; // i-plane stride of `off` in elements
constexpr int SWAP_D2 = 589824;        // 768^2
constexpr int CLEAN_D2 = 586756;       // 766^2

// Gaussian kernel sigma=2, truncate=4 -> radius 8, normalized (precomputed)
__device__ __constant__ float GK[17] = {
    6.691628e-05f, 4.363490e-04f, 2.215963e-03f, 8.764304e-03f,
    2.699596e-02f, 6.475994e-02f, 1.209875e-01f, 1.760358e-01f,
    1.9947466e-01f, 1.760358e-01f, 1.209875e-01f, 6.475994e-02f,
    2.699596e-02f, 8.764304e-03f, 2.215963e-03f, 4.363490e-04f,
    6.691628e-05f};

// ---------------------------------------------------------------------------
// Pass 1: gather-formulated glass swap + fp16 planar repack.
// Key trick vs R2: candidate orders are monotone in a fixed scan sequence, so
// the scatter-max argmax is just "last hit wins" — zero order arithmetic.
// Each halo q is packed into 4 bytes: (dw0+2)|(dh0+2)<<8|(dw1+2)<<16|(dh1+2)<<24
// (sentinel 0xFFFFFFFF where masked), so a candidate test is one 16-bit compare.
// Priority sequence (increasing reference order):
//   all i=0 write2 cands (ddy=1..-2, ddx=1..-2) < i=1 cands with ddy*REG+ddx>0
//   < self-write (i=1 write1) < remaining i=1 cands.
// ---------------------------------------------------------------------------
constexpr int TX = 32, TY = 8;
constexpr int HX = TX + 3, HY = TY + 3;  // 35 x 11 halo

__global__ __launch_bounds__(256) void swap_gather(
    const float* __restrict__ img, const int* __restrict__ off,
    __half* __restrict__ A) {
  int x0 = blockIdx.x * TX, y0 = blockIdx.y * TY;
  int tx = threadIdx.x & 31, ty = threadIdx.x >> 5;
  int px = x0 + tx, py = y0 + ty;
  int plin = py * Ww + px;
  int srcoff = 0;  // src - plin

  // Block-uniform fast path: halo entirely inside clean circle -> no writers.
  int mxx = max(abs(1024 - (x0 - 1)), abs(1024 - (x0 + TX + 1)));
  int mxy = max(abs(1024 - (y0 - 1)), abs(1024 - (y0 + TY + 1)));
  if (mxx * mxx + mxy * mxy >= SWAP_D2) {
    __shared__ unsigned sh[HY * HX];
    for (int e = threadIdx.x; e < HY * HX; e += 256) {
      int ly = e / HX, lx = e - ly * HX;
      int qy = y0 - 1 + ly, qx = x0 - 1 + lx;
      unsigned v = 0xFFFFFFFFu;
      int dcx = 1024 - qx, dcy = 1024 - qy;
      if (qy >= 2 && qy <= 2046 && qx >= 2 && qx <= 2046 &&
          dcx * dcx + dcy * dcy >= SWAP_D2) {
        int base = ((qy - 2) * REG + (qx - 2)) * 2;
        const int2 a0 = *(const int2*)&off[base];          // {dh0, dw0}
        const int2 a1 = *(const int2*)&off[RBASE + base];  // {dh1, dw1}
        v = (unsigned)(a0.y + 2) | ((unsigned)(a0.x + 2) << 8) |
            ((unsigned)(a1.y + 2) << 16) | ((unsigned)(a1.x + 2) << 24);
      }
      sh[e] = v;
    }
    __syncthreads();

    unsigned w[4][4];
#pragma unroll
    for (int dyi = 0; dyi < 4; ++dyi)
#pragma unroll
      for (int dxi = 0; dxi < 4; ++dxi)
        w[dyi][dxi] = sh[(ty + dyi) * HX + (tx + dxi)];

#define CANDC(dyi, dxi) ((unsigned)((1 - (dxi)) + 2) | ((unsigned)((1 - (dyi)) + 2) << 8))
#define OFFC(dyi, dxi) (-(1 - (dyi)) * Ww - (1 - (dxi)))
#define CAND0(dyi, dxi) \
  if ((w[dyi][dxi] & 0xFFFFu) == CANDC(dyi, dxi)) srcoff = OFFC(dyi, dxi);
#define CAND1(dyi, dxi) \
  if ((w[dyi][dxi] >> 16) == CANDC(dyi, dxi)) srcoff = OFFC(dyi, dxi);

    // i = 0 write2 candidates, in increasing-order sequence
    CAND0(0, 0) CAND0(0, 1) CAND0(0, 2) CAND0(0, 3)
    CAND0(1, 0) CAND0(1, 1) CAND0(1, 2) CAND0(1, 3)
    CAND0(2, 0) CAND0(2, 1) CAND0(2, 2) CAND0(2, 3)
    CAND0(3, 0) CAND0(3, 1) CAND0(3, 2) CAND0(3, 3)
    // i = 1: cands with ddy*REG+ddx >= 1, then self-write, then the rest
    CAND1(0, 0) CAND1(0, 1) CAND1(0, 2) CAND1(0, 3)
    CAND1(1, 0)
    {  // self-write (i=1 write1): src = p + off1[p]
      unsigned wc = w[1][1];
      if ((wc >> 24) != 0xFFu) {
        int dh1 = (int)((wc >> 24) & 0xFFu) - 2;
        int dw1 = (int)((wc >> 16) & 0xFFu) - 2;
        srcoff = dh1 * Ww + dw1;
      }
    }
    CAND1(1, 1) CAND1(1, 2) CAND1(1, 3)
    CAND1(2, 0) CAND1(2, 1) CAND1(2, 2) CAND1(2, 3)
    CAND1(3, 0) CAND1(3, 1) CAND1(3, 2) CAND1(3, 3)
#undef CANDC
#undef OFFC
#undef CAND0
#undef CAND1
  }

  int src = plin + srcoff;
  float r = img[src * 3 + 0];
  float g = img[src * 3 + 1];
  float b = img[src * 3 + 2];
  A[plin] = __float2half(r);
  A[HW + plin] = __float2half(g);
  A[2 * HW + plin] = __float2half(b);
}

// ---------------------------------------------------------------------------
// Pass 2: vertical 17-tap blur. 4 cols/thread (uint2 = 512 B per wave per row
// for DRAM granularity), 16 rows/thread register accumulation. 1-D grid with
// XCD band swizzle: blk&7 = XCD owns a contiguous y-band, y varies fastest so
// the 16-row halo re-read hits that XCD's L2.
// ---------------------------------------------------------------------------
constexpr int YPT = 16;
__global__ __launch_bounds__(256) void vblur(const __half* __restrict__ A,
                                             __half* __restrict__ B) {
  int b = blockIdx.x;
  int xcd = b & 7, r = b >> 3;          // 768 blocks: r in [0,96)
  int ystrip = (xcd << 4) | (r & 15);   // 128 strips, 16 per XCD band
  int rem = r >> 4;                     // 0..5
  int xb = rem & 1, c = rem >> 1;
  int x0 = (xb * 256 + threadIdx.x) * 4;
  int y0 = ystrip * YPT;
  const __half* Ap = A + (size_t)c * HW;
  __half* Bp = B + (size_t)c * HW;

  float acc[YPT][4];
#pragma unroll
  for (int k = 0; k < YPT; ++k)
#pragma unroll
    for (int q = 0; q < 4; ++q) acc[k][q] = 0.f;

#pragma unroll
  for (int j = 0; j < YPT + 16; ++j) {
    int ys = y0 - 8 + j;
    ys = ys < 0 ? 0 : (ys > Hh - 1 ? Hh - 1 : ys);  // mode='nearest'
    uint2 raw = *(const uint2*)&Ap[(size_t)ys * Ww + x0];
    __half2 h01 = *(__half2*)&raw.x;
    __half2 h23 = *(__half2*)&raw.y;
    float2 v01 = __half22float2(h01);
    float2 v23 = __half22float2(h23);
#pragma unroll
    for (int k = 0; k < YPT; ++k) {
      int t = j - k;
      if (t >= 0 && t <= 16) {
        float gk = GK[t];
        acc[k][0] += gk * v01.x;
        acc[k][1] += gk * v01.y;
        acc[k][2] += gk * v23.x;
        acc[k][3] += gk * v23.y;
      }
    }
  }
#pragma unroll
  for (int k = 0; k < YPT; ++k) {
    uint2 o;
    __half2 h01 = __float22half2_rn(make_float2(acc[k][0], acc[k][1]));
    __half2 h23 = __float22half2_rn(make_float2(acc[k][2], acc[k][3]));
    o.x = *(unsigned*)&h01;
    o.y = *(unsigned*)&h23;
    *(uint2*)&Bp[(size_t)(y0 + k) * Ww + x0] = o;
  }
}

// ---------------------------------------------------------------------------
// Pass 3: horizontal 17-tap blur + clip + compose. 512-px row tiles, half2
// staging (~1 KB contiguous per row visit), 2 px/thread, channel loop inside
// so each thread's out stores are 6 contiguous floats.
// ---------------------------------------------------------------------------
__global__ __launch_bounds__(256) void hblur_compose(
    const __half* __restrict__ B, const float* __restrict__ img,
    float* __restrict__ out) {
  __shared__ float tile[528 + 1];
  int tid = threadIdx.x;
  int xs = blockIdx.x * 512;
  int y = blockIdx.y;
  float br[3][2];

  for (int c = 0; c < 3; ++c) {
    const __half* Bp = B + (size_t)c * HW + (size_t)y * Ww;
    __syncthreads();  // protect tile from previous channel's readers
    // stage B[xs-8 .. xs+519] -> tile[0..527]
    for (int e = tid; e < 264; e += 256) {
      int xg = xs - 8 + 2 * e;
      float2 v;
      if (xg >= 0 && xg + 1 <= Ww - 1) {
        __half2 h = *(const __half2*)&Bp[xg];
        v = __half22float2(h);
      } else {
        int xlo = xg < 0 ? 0 : (xg > Ww - 1 ? Ww - 1 : xg);
        int xhi = xg + 1 < 0 ? 0 : (xg + 1 > Ww - 1 ? Ww - 1 : xg + 1);
        v = make_float2(__half2float(Bp[xlo]), __half2float(Bp[xhi]));
      }
      *(float2*)&tile[2 * e] = v;
    }
    __syncthreads();
    float f[19];
#pragma unroll
    for (int j = 0; j < 19; ++j) f[j] = tile[2 * tid + j];
    float s0 = 0.f, s1 = 0.f;
#pragma unroll
    for (int j = 0; j < 17; ++j) {
      s0 += GK[j] * f[j];
      s1 += GK[j] * f[j + 1];
    }
    br[c][0] = s0;
    br[c][1] = s1;
  }

  int x = xs + 2 * tid;
#pragma unroll
  for (int u = 0; u < 2; ++u) {
    int xu = x + u;
    int dx = 1024 - xu, dy = 1024 - y;
    bool clean = (xu >= 2 && xu <= 2046 && y >= 2 && y <= 2046 &&
                  dx * dx + dy * dy < CLEAN_D2);
    int p3 = (y * Ww + xu) * 3;
    if (clean) {
      out[p3 + 0] = img[p3 + 0];
      out[p3 + 1] = img[p3 + 1];
      out[p3 + 2] = img[p3 + 2];
    } else {
#pragma unroll
      for (int c = 0; c < 3; ++c) {
        float v = br[c][u];
        v = v < 0.f ? 0.f : (v > 255.f ? 255.f : v);
        out[p3 + c] = v;
      }
    }
  }
}

extern "C" void kernel_launch(void* const* d_in, const int* in_sizes, int n_in,
                              void* d_out, int out_size, void* d_ws,
                              size_t ws_size, hipStream_t stream) {
  const float* img = (const float*)d_in[0];
  const int* off = (const int*)d_in[1];
  float* out = (float*)d_out;

  // Workspace: A (fp16 x 3 planes, 24 MB) | B (fp16 x 3 planes, 24 MB)
  __half* A = (__half*)d_ws;
  __half* Bp = A + (size_t)3 * HW;

  swap_gather<<<dim3(Ww / TX, Hh / TY), 256, 0, stream>>>(img, off, A);
  vblur<<<768, 256, 0, stream>>>(A, Bp);
  hblur_compose<<<dim3(Ww / 512, Hh), 256, 0, stream>>>(Bp, img, out);
}